// Round 4
// baseline (528.060 us; speedup 1.0000x reference)
//
#include <hip/hip_runtime.h>
#include <hip/hip_bf16.h>

typedef __attribute__((ext_vector_type(4))) float f32x4;
typedef __attribute__((ext_vector_type(8))) short bf16x8;

#define DINF 1e30f

// ---------------------------------------------------------------------------
// round-to-nearest-even fp32 -> bf16 bits (inputs are finite gaussians)
__device__ __forceinline__ unsigned short f2bf(float f) {
    unsigned int u = __builtin_bit_cast(unsigned int, f);
    u += 0x7FFFu + ((u >> 16) & 1u);
    return (unsigned short)(u >> 16);
}

// ---------------------------------------------------------------------------
// Kernel 1: L2-normalize each 768-dim row, emit bf16.
__global__ __launch_bounds__(256) void norm_bf16_kernel(
    const float* __restrict__ s1, const float* __restrict__ s2,
    __hip_bfloat16* __restrict__ o1, __hip_bfloat16* __restrict__ o2) {
    const int gb = blockIdx.x;
    const float* in;
    __hip_bfloat16* out;
    int rowbase;
    if (gb < 4096) { in = s1; out = o1; rowbase = gb * 4; }
    else           { in = s2; out = o2; rowbase = (gb - 4096) * 4; }
    const int wv = threadIdx.x >> 6;
    const int l  = threadIdx.x & 63;
    const int row = rowbase + wv;

    const float* rp = in + (size_t)row * 768 + l * 4;
    float4 x0 = *(const float4*)(rp);
    float4 x1 = *(const float4*)(rp + 256);
    float4 x2 = *(const float4*)(rp + 512);

    float s = x0.x*x0.x + x0.y*x0.y + x0.z*x0.z + x0.w*x0.w
            + x1.x*x1.x + x1.y*x1.y + x1.z*x1.z + x1.w*x1.w
            + x2.x*x2.x + x2.y*x2.y + x2.z*x2.z + x2.w*x2.w;
#pragma unroll
    for (int off = 32; off > 0; off >>= 1) s += __shfl_xor(s, off, 64);

    const float inv = 1.0f / fmaxf(sqrtf(s), 1e-12f);

    __hip_bfloat16* op = out + (size_t)row * 768 + l * 4;
    ushort4 o;
    o.x = f2bf(x0.x*inv); o.y = f2bf(x0.y*inv); o.z = f2bf(x0.z*inv); o.w = f2bf(x0.w*inv);
    *(ushort4*)(op) = o;
    o.x = f2bf(x1.x*inv); o.y = f2bf(x1.y*inv); o.z = f2bf(x1.z*inv); o.w = f2bf(x1.w*inv);
    *(ushort4*)(op + 256) = o;
    o.x = f2bf(x2.x*inv); o.y = f2bf(x2.y*inv); o.z = f2bf(x2.z*inv); o.w = f2bf(x2.w*inv);
    *(ushort4*)(op + 512) = o;
}

// ---------------------------------------------------------------------------
// Kernel 2: dist = 1 - A·B^T via bf16 MFMA. 128x128 tile, BK=64, 4 waves.
// (unchanged from round 2 -- passed)
#define GLOAD_LDS16(g, l)                                                      \
    __builtin_amdgcn_global_load_lds(                                          \
        (const __attribute__((address_space(1))) void*)(g),                    \
        (__attribute__((address_space(3))) void*)(l), 16, 0, 0)

__global__ __launch_bounds__(256) void gemm_dist_kernel(
    const __hip_bfloat16* __restrict__ A, const __hip_bfloat16* __restrict__ B,
    float* __restrict__ dist) {
    __shared__ __hip_bfloat16 lA[128 * 64];  // [row][k], rows of 128B
    __shared__ __hip_bfloat16 lB[128 * 64];

    const int blk  = (blockIdx.x & 7) * 128 + (blockIdx.x >> 3);
    const int b    = blk >> 6;
    const int tile = blk & 63;
    const int tm = tile >> 3, tn = tile & 7;
    const int tid  = threadIdx.x;
    const int lane = tid & 63, w = tid >> 6;
    const int lr = lane & 15, lg = lane >> 4;
    const int wm = w >> 1, wn = w & 1;

    const __hip_bfloat16* Ab = A + (size_t)b * (1024 * 768) + (size_t)(tm * 128) * 768;
    const __hip_bfloat16* Bb = B + (size_t)b * (1024 * 768) + (size_t)(tn * 128) * 768;

    const int srow = tid >> 3;        // 0..31 (row within 32-row chunk)
    const int scol = (tid & 7) * 8;   // k-octet (8 bf16 = 16B per lane)

    char* lAb = (char*)lA;
    char* lBb = (char*)lB;

    f32x4 acc[4][4];
#pragma unroll
    for (int m = 0; m < 4; ++m)
#pragma unroll
        for (int n = 0; n < 4; ++n) acc[m][n] = (f32x4){0.f, 0.f, 0.f, 0.f};

    for (int k0 = 0; k0 < 768; k0 += 64) {
#pragma unroll
        for (int q = 0; q < 4; ++q) {
            GLOAD_LDS16(Ab + (size_t)(q * 32 + srow) * 768 + k0 + scol,
                        lAb + q * 4096 + w * 1024);
            GLOAD_LDS16(Bb + (size_t)(q * 32 + srow) * 768 + k0 + scol,
                        lBb + q * 4096 + w * 1024);
        }
        __syncthreads();

#pragma unroll
        for (int ks = 0; ks < 64; ks += 32) {
            bf16x8 af[4], bfr[4];
#pragma unroll
            for (int m = 0; m < 4; ++m)
                af[m] = *(const bf16x8*)&lA[(wm * 64 + m * 16 + lr) * 64 + ks + lg * 8];
#pragma unroll
            for (int n = 0; n < 4; ++n)
                bfr[n] = *(const bf16x8*)&lB[(wn * 64 + n * 16 + lr) * 64 + ks + lg * 8];
#pragma unroll
            for (int m = 0; m < 4; ++m)
#pragma unroll
                for (int n = 0; n < 4; ++n)
                    acc[m][n] = __builtin_amdgcn_mfma_f32_16x16x32_bf16(af[m], bfr[n], acc[m][n], 0, 0, 0);
        }
        __syncthreads();
    }

    float* Drow = dist + (size_t)b * (1024 * 1024);
#pragma unroll
    for (int m = 0; m < 4; ++m)
#pragma unroll
        for (int n = 0; n < 4; ++n)
#pragma unroll
            for (int r = 0; r < 4; ++r) {
                const int row = tm * 128 + wm * 64 + m * 16 + lg * 4 + r;
                const int col = tn * 128 + wn * 64 + n * 16 + lr;
                Drow[(size_t)row * 1024 + col] = 1.0f - acc[m][n][r];
            }
}

// ---------------------------------------------------------------------------
// Kernel 3: DTW DP. One wave per batch. Lane t owns cols [16t,16t+16).
// Skew 2: step k -> lane t processes row r = k - 2t (round-2 verified math).
//
// ROUND-4 FIX: round 3's inline-asm register prefetch was racy (regalloc may
// copy an asm-output vreg between issue and the delayed vmcnt wait). Now the
// prefetch goes through an 8-slot LDS ring via global_load_lds DMA: in-flight
// data never lives in an allocatable register. Slot = 4 chunks x 64 lanes x
// 16B, lane-linear (the DMA's fixed dest pattern); per-lane global addresses
// do the row gather (r depends on lane). Discipline per body k:
//   lgkmcnt(0)                      ; slot k&7's prior ds_read fully done
//   issue 4 DMA for step k+8       -> slot k&7
//   vmcnt(28)                       ; 7 slots x 4 loads stay in flight ->
//                                     slot k+1 landed (in-order retire)
//   ds_read slot (k+1)&7 -> B_{(k+1)&1}   (plain HIP float4; reg dbuf hides
//                                          LDS latency; compiler tracks lgkm)
//   STEP k on B_{k&1}
// The "memory"-clobber asm waitcnts pin DMA issues and ds_reads (both real
// memory ops); STEP's pure-register math may float freely (harmless).

#define LGKM0    asm volatile("s_waitcnt lgkmcnt(0)" ::: "memory")
#define VWAIT(n) asm volatile("s_waitcnt vmcnt(" #n ")" ::: "memory")

#define GLDMA16(g, l)                                                          \
    __builtin_amdgcn_global_load_lds(                                          \
        (const __attribute__((address_space(1))) void*)(g),                    \
        (__attribute__((address_space(3))) void*)(l), 16, 0, 0)

#define LOADB(kk, SLOT) do {                                                   \
    int r_ = (kk) - tt;                                                        \
    r_ = r_ < 0 ? 0 : (r_ > 1023 ? 1023 : r_);                                 \
    const char* g_ = DbB + ((size_t)r_ << 12);                                 \
    GLDMA16(g_,      &ring[SLOT][0][0]);                                       \
    GLDMA16(g_ + 16, &ring[SLOT][1][0]);                                       \
    GLDMA16(g_ + 32, &ring[SLOT][2][0]);                                       \
    GLDMA16(g_ + 48, &ring[SLOT][3][0]);                                       \
} while (0)

#define DSREAD(S, P) do {                                                      \
    P##_0 = ring[S][0][t]; P##_1 = ring[S][1][t];                              \
    P##_2 = ring[S][2][t]; P##_3 = ring[S][3][t];                              \
} while (0)

// lin = a2 (neighbor col boundary, row r), dg = a3 (row r-1).
#define STEPBODY(P, E0EXPR) do {                                               \
    float e0_ = (E0EXPR);                                                      \
    float c0_  = P##_0.x + e0_;                                                \
    float c1_  = P##_0.y + fminf(fminf(p1,  p0),  c0_);                        \
    float c2_  = P##_0.z + fminf(fminf(p2,  p1),  c1_);                        \
    float c3_  = P##_0.w + fminf(fminf(p3,  p2),  c2_);                        \
    float c4_  = P##_1.x + fminf(fminf(p4,  p3),  c3_);                        \
    float c5_  = P##_1.y + fminf(fminf(p5,  p4),  c4_);                        \
    float c6_  = P##_1.z + fminf(fminf(p6,  p5),  c5_);                        \
    float c7_  = P##_1.w + fminf(fminf(p7,  p6),  c6_);                        \
    float c8_  = P##_2.x + fminf(fminf(p8,  p7),  c7_);                        \
    float c9_  = P##_2.y + fminf(fminf(p9,  p8),  c8_);                        \
    float c10_ = P##_2.z + fminf(fminf(p10, p9),  c9_);                        \
    float c11_ = P##_2.w + fminf(fminf(p11, p10), c10_);                       \
    float c12_ = P##_3.x + fminf(fminf(p12, p11), c11_);                       \
    float c13_ = P##_3.y + fminf(fminf(p13, p12), c12_);                       \
    float c14_ = P##_3.z + fminf(fminf(p14, p13), c13_);                       \
    float c15_ = P##_3.w + fminf(fminf(p15, p14), c14_);                       \
    p0=c0_; p1=c1_; p2=c2_; p3=c3_; p4=c4_; p5=c5_; p6=c6_; p7=c7_;            \
    p8=c8_; p9=c9_; p10=c10_; p11=c11_; p12=c12_; p13=c13_; p14=c14_; p15=c15_;\
    a3 = a2; a2 = a1;                                                          \
    a1 = __shfl_up(c15_, 1, 64);                                               \
    a1 = lane0 ? DINF : a1;                                                    \
} while (0)

#define STEPB(P)       STEPBODY(P, fminf(fminf(p0, a3), a2))
#define STEPB_FIRST(P) STEPBODY(P, lane0 ? 0.0f : fminf(fminf(p0, a3), a2))

__global__ __launch_bounds__(64) void dtw_dp_kernel(
    const float* __restrict__ dist, float* __restrict__ out) {
    __shared__ float4 ring[8][4][64];  // 32 KiB: [slot][chunk][lane]

    const int b = blockIdx.x;
    const int t = threadIdx.x;
    const int tt = 2 * t;
    const bool lane0 = (t == 0);
    // lane t's column block base, in bytes: dist[b] + t*16 floats
    const char* DbB = (const char*)(dist + ((size_t)b << 20)) + t * 64;

    float p0 = DINF, p1 = DINF, p2 = DINF, p3 = DINF,
          p4 = DINF, p5 = DINF, p6 = DINF, p7 = DINF,
          p8 = DINF, p9 = DINF, p10 = DINF, p11 = DINF,
          p12 = DINF, p13 = DINF, p14 = DINF, p15 = DINF;
    float a1 = DINF, a2 = DINF, a3 = DINF;

    float4 X_0, X_1, X_2, X_3;   // B0: rows for even steps
    float4 Y_0, Y_1, Y_2, Y_3;   // B1: rows for odd steps

    // prologue: fill all 8 slots (steps 0..7), land slot 0, read it.
    LOADB(0, 0); LOADB(1, 1); LOADB(2, 2); LOADB(3, 3);
    LOADB(4, 4); LOADB(5, 5); LOADB(6, 6); LOADB(7, 7);
    VWAIT(28);
    DSREAD(0, X);

    // bodies 0..7 (explicit; step 0 has the dtw[0][0] special case)
    LGKM0; LOADB(8,  0); VWAIT(28); DSREAD(1, Y); STEPB_FIRST(X);
    LGKM0; LOADB(9,  1); VWAIT(28); DSREAD(2, X); STEPB(Y);
    LGKM0; LOADB(10, 2); VWAIT(28); DSREAD(3, Y); STEPB(X);
    LGKM0; LOADB(11, 3); VWAIT(28); DSREAD(4, X); STEPB(Y);
    LGKM0; LOADB(12, 4); VWAIT(28); DSREAD(5, Y); STEPB(X);
    LGKM0; LOADB(13, 5); VWAIT(28); DSREAD(6, X); STEPB(Y);
    LGKM0; LOADB(14, 6); VWAIT(28); DSREAD(7, Y); STEPB(X);
    LGKM0; LOADB(15, 7); VWAIT(28); DSREAD(0, X); STEPB(Y);

    // bodies 8..1135 (141 iterations x 8 steps)
#pragma unroll 1
    for (int k = 8; k < 1136; k += 8) {
        LGKM0; LOADB(k + 8,  0); VWAIT(28); DSREAD(1, Y); STEPB(X);
        LGKM0; LOADB(k + 9,  1); VWAIT(28); DSREAD(2, X); STEPB(Y);
        LGKM0; LOADB(k + 10, 2); VWAIT(28); DSREAD(3, Y); STEPB(X);
        LGKM0; LOADB(k + 11, 3); VWAIT(28); DSREAD(4, X); STEPB(Y);
        LGKM0; LOADB(k + 12, 4); VWAIT(28); DSREAD(5, Y); STEPB(X);
        LGKM0; LOADB(k + 13, 5); VWAIT(28); DSREAD(6, X); STEPB(Y);
        LGKM0; LOADB(k + 14, 6); VWAIT(28); DSREAD(7, Y); STEPB(X);
        LGKM0; LOADB(k + 15, 7); VWAIT(28); DSREAD(0, X); STEPB(Y);
    }

    // bodies 1136..1141 (still issuing; last DMA targets step 1149)
    LGKM0; LOADB(1144, 0); VWAIT(28); DSREAD(1, Y); STEPB(X);
    LGKM0; LOADB(1145, 1); VWAIT(28); DSREAD(2, X); STEPB(Y);
    LGKM0; LOADB(1146, 2); VWAIT(28); DSREAD(3, Y); STEPB(X);
    LGKM0; LOADB(1147, 3); VWAIT(28); DSREAD(4, X); STEPB(Y);
    LGKM0; LOADB(1148, 4); VWAIT(28); DSREAD(5, Y); STEPB(X);
    LGKM0; LOADB(1149, 5); VWAIT(28); DSREAD(6, X); STEPB(Y);

    // tail 1142..1149: drain the DMA queue
    VWAIT(24); DSREAD(7, Y); STEPB(X);
    VWAIT(20); DSREAD(0, X); STEPB(Y);
    VWAIT(16); DSREAD(1, Y); STEPB(X);
    VWAIT(12); DSREAD(2, X); STEPB(Y);
    VWAIT(8);  DSREAD(3, Y); STEPB(X);
    VWAIT(4);  DSREAD(4, X); STEPB(Y);
    VWAIT(0);  DSREAD(5, Y); STEPB(X);
    STEPB(Y);

    // Lane 63's final step is k = 1023 + 2*63 = 1149 -> p15 = dtw[1023][1023].
    if (t == 63) out[b] = 1.0f / (1.0f + p15 * (1.0f / 2048.0f));
}

// ---------------------------------------------------------------------------
extern "C" void kernel_launch(void* const* d_in, const int* in_sizes, int n_in,
                              void* d_out, int out_size, void* d_ws, size_t ws_size,
                              hipStream_t stream) {
    const float* s1 = (const float*)d_in[0];
    const float* s2 = (const float*)d_in[1];
    float* out = (float*)d_out;

    char* ws = (char*)d_ws;
    __hip_bfloat16* Abf = (__hip_bfloat16*)(ws);                 // 25165824 B
    __hip_bfloat16* Bbf = (__hip_bfloat16*)(ws + 25165824);      // 25165824 B
    float* dist = (float*)(ws + 50331648);                       // 67108864 B

    norm_bf16_kernel<<<8192, 256, 0, stream>>>(s1, s2, Abf, Bbf);
    gemm_dist_kernel<<<16 * 64, 256, 0, stream>>>(Abf, Bbf, dist);
    dtw_dp_kernel<<<16, 64, 0, stream>>>(dist, out);
}

// Round 5
// 465.068 us; speedup vs baseline: 1.1354x; 1.1354x over previous
//
#include <hip/hip_runtime.h>
#include <hip/hip_bf16.h>

typedef __attribute__((ext_vector_type(4))) float f32x4;
typedef __attribute__((ext_vector_type(8))) short bf16x8;

#define DINF 1e30f

// ---------------------------------------------------------------------------
// round-to-nearest-even fp32 -> bf16 bits (inputs are finite gaussians)
__device__ __forceinline__ unsigned short f2bf(float f) {
    unsigned int u = __builtin_bit_cast(unsigned int, f);
    u += 0x7FFFu + ((u >> 16) & 1u);
    return (unsigned short)(u >> 16);
}

// ---------------------------------------------------------------------------
// Kernel 1: L2-normalize each 768-dim row, emit bf16.
__global__ __launch_bounds__(256) void norm_bf16_kernel(
    const float* __restrict__ s1, const float* __restrict__ s2,
    __hip_bfloat16* __restrict__ o1, __hip_bfloat16* __restrict__ o2) {
    const int gb = blockIdx.x;
    const float* in;
    __hip_bfloat16* out;
    int rowbase;
    if (gb < 4096) { in = s1; out = o1; rowbase = gb * 4; }
    else           { in = s2; out = o2; rowbase = (gb - 4096) * 4; }
    const int wv = threadIdx.x >> 6;
    const int l  = threadIdx.x & 63;
    const int row = rowbase + wv;

    const float* rp = in + (size_t)row * 768 + l * 4;
    float4 x0 = *(const float4*)(rp);
    float4 x1 = *(const float4*)(rp + 256);
    float4 x2 = *(const float4*)(rp + 512);

    float s = x0.x*x0.x + x0.y*x0.y + x0.z*x0.z + x0.w*x0.w
            + x1.x*x1.x + x1.y*x1.y + x1.z*x1.z + x1.w*x1.w
            + x2.x*x2.x + x2.y*x2.y + x2.z*x2.z + x2.w*x2.w;
#pragma unroll
    for (int off = 32; off > 0; off >>= 1) s += __shfl_xor(s, off, 64);

    const float inv = 1.0f / fmaxf(sqrtf(s), 1e-12f);

    __hip_bfloat16* op = out + (size_t)row * 768 + l * 4;
    ushort4 o;
    o.x = f2bf(x0.x*inv); o.y = f2bf(x0.y*inv); o.z = f2bf(x0.z*inv); o.w = f2bf(x0.w*inv);
    *(ushort4*)(op) = o;
    o.x = f2bf(x1.x*inv); o.y = f2bf(x1.y*inv); o.z = f2bf(x1.z*inv); o.w = f2bf(x1.w*inv);
    *(ushort4*)(op + 256) = o;
    o.x = f2bf(x2.x*inv); o.y = f2bf(x2.y*inv); o.z = f2bf(x2.z*inv); o.w = f2bf(x2.w*inv);
    *(ushort4*)(op + 512) = o;
}

// ---------------------------------------------------------------------------
// Kernel 2: GEMM -> SKEWED bf16 distance matrix.
// skew[b][row + 2*(col>>4)][col] = bf16(1 - dot(A[row], B[col])).
// Skew rows 0..1149, padded to 1152. The DP kernel's step k then reads
// skew row k as ONE contiguous 2KB line (the whole anti-diagonal band).
#define GLOAD_LDS16(g, l)                                                      \
    __builtin_amdgcn_global_load_lds(                                          \
        (const __attribute__((address_space(1))) void*)(g),                    \
        (__attribute__((address_space(3))) void*)(l), 16, 0, 0)

__global__ __launch_bounds__(256) void gemm_dist_kernel(
    const __hip_bfloat16* __restrict__ A, const __hip_bfloat16* __restrict__ B,
    __hip_bfloat16* __restrict__ skew) {
    __shared__ __hip_bfloat16 lA[128 * 64];  // [row][k], rows of 128B
    __shared__ __hip_bfloat16 lB[128 * 64];

    const int blk  = (blockIdx.x & 7) * 128 + (blockIdx.x >> 3);
    const int b    = blk >> 6;
    const int tile = blk & 63;
    const int tm = tile >> 3, tn = tile & 7;
    const int tid  = threadIdx.x;
    const int lane = tid & 63, w = tid >> 6;
    const int lr = lane & 15, lg = lane >> 4;
    const int wm = w >> 1, wn = w & 1;

    const __hip_bfloat16* Ab = A + (size_t)b * (1024 * 768) + (size_t)(tm * 128) * 768;
    const __hip_bfloat16* Bb = B + (size_t)b * (1024 * 768) + (size_t)(tn * 128) * 768;

    const int srow = tid >> 3;        // 0..31 (row within 32-row chunk)
    const int scol = (tid & 7) * 8;   // k-octet (8 bf16 = 16B per lane)

    char* lAb = (char*)lA;
    char* lBb = (char*)lB;

    f32x4 acc[4][4];
#pragma unroll
    for (int m = 0; m < 4; ++m)
#pragma unroll
        for (int n = 0; n < 4; ++n) acc[m][n] = (f32x4){0.f, 0.f, 0.f, 0.f};

    for (int k0 = 0; k0 < 768; k0 += 64) {
#pragma unroll
        for (int q = 0; q < 4; ++q) {
            GLOAD_LDS16(Ab + (size_t)(q * 32 + srow) * 768 + k0 + scol,
                        lAb + q * 4096 + w * 1024);
            GLOAD_LDS16(Bb + (size_t)(q * 32 + srow) * 768 + k0 + scol,
                        lBb + q * 4096 + w * 1024);
        }
        __syncthreads();

#pragma unroll
        for (int ks = 0; ks < 64; ks += 32) {
            bf16x8 af[4], bfr[4];
#pragma unroll
            for (int m = 0; m < 4; ++m)
                af[m] = *(const bf16x8*)&lA[(wm * 64 + m * 16 + lr) * 64 + ks + lg * 8];
#pragma unroll
            for (int n = 0; n < 4; ++n)
                bfr[n] = *(const bf16x8*)&lB[(wn * 64 + n * 16 + lr) * 64 + ks + lg * 8];
#pragma unroll
            for (int m = 0; m < 4; ++m)
#pragma unroll
                for (int n = 0; n < 4; ++n)
                    acc[m][n] = __builtin_amdgcn_mfma_f32_16x16x32_bf16(af[m], bfr[n], acc[m][n], 0, 0, 0);
        }
        __syncthreads();
    }

    unsigned short* S = (unsigned short*)skew + (size_t)b * (1152 * 1024);
#pragma unroll
    for (int m = 0; m < 4; ++m)
#pragma unroll
        for (int n = 0; n < 4; ++n) {
            const int cb = tn * 128 + wn * 64 + n * 16;       // col base (mult of 16)
            const int soff = 2 * (cb >> 4);                   // skew offset for this col block
#pragma unroll
            for (int r = 0; r < 4; ++r) {
                const int row = tm * 128 + wm * 64 + m * 16 + lg * 4 + r;
                S[(size_t)(row + soff) * 1024 + cb + lr] = f2bf(1.0f - acc[m][n][r]);
            }
        }
}

// ---------------------------------------------------------------------------
// Kernel 3: DTW DP. One wave per batch. Lane t owns cols [16t,16t+16).
// Skew 2: step k -> lane t processes row r = k - 2t.
//
// ROUND-5 FIX: round 4's ring was correct but each DMA was a 64-line gather
// (per-lane row) -> ~960 cyc/step of address processing. The skewed layout
// makes step k's band ONE contiguous 2KB row: 2 DMAs/body, wave-uniform row,
// lane-linear src AND dest (the DMA's ideal pattern). Ring discipline is
// byte-for-byte round 4's (proven correct), with counts halved:
//   lgkmcnt(0); issue 2 DMA for step k+8; vmcnt(14)  [7 slots x 2 in flight]
//   ds_read slot (k+1)&7 -> reg dbuf; STEP k.
// Hole cells of the skew parallelogram are zeroed by a memsetAsync before
// the GEMM (d=0 is absorbed by the 1e30 min-plus flow).

#define LGKM0    asm volatile("s_waitcnt lgkmcnt(0)" ::: "memory")
#define VWAIT(n) asm volatile("s_waitcnt vmcnt(" #n ")" ::: "memory")

#define GLDMA16(g, l)                                                          \
    __builtin_amdgcn_global_load_lds(                                          \
        (const __attribute__((address_space(1))) void*)(g),                    \
        (__attribute__((address_space(3))) void*)(l), 16, 0, 0)

// step kk's band = skew row kk: 2KB contiguous; lane t's 32B at +t*32.
#define LOADB(kk, SLOT) do {                                                   \
    const char* g_ = Sb + ((size_t)(kk) << 11) + (t << 5);                     \
    GLDMA16(g_,      &ring[SLOT][0][0]);                                       \
    GLDMA16(g_ + 16, &ring[SLOT][1][0]);                                       \
} while (0)

#define DSREAD(S, P) do {                                                      \
    P##_0 = ring[S][0][t]; P##_1 = ring[S][1][t];                              \
} while (0)

// Unpack 16 bf16 cols from two float4s; min-plus chain; boundary shfl.
// lin = a2 (neighbor boundary, row r), dg = a3 (row r-1).
#define STEPBODY(P, E0EXPR) do {                                               \
    unsigned u0_ = __builtin_bit_cast(unsigned, P##_0.x);                      \
    unsigned u1_ = __builtin_bit_cast(unsigned, P##_0.y);                      \
    unsigned u2_ = __builtin_bit_cast(unsigned, P##_0.z);                      \
    unsigned u3_ = __builtin_bit_cast(unsigned, P##_0.w);                      \
    unsigned u4_ = __builtin_bit_cast(unsigned, P##_1.x);                      \
    unsigned u5_ = __builtin_bit_cast(unsigned, P##_1.y);                      \
    unsigned u6_ = __builtin_bit_cast(unsigned, P##_1.z);                      \
    unsigned u7_ = __builtin_bit_cast(unsigned, P##_1.w);                      \
    float d0_  = __builtin_bit_cast(float, u0_ << 16);                         \
    float d1_  = __builtin_bit_cast(float, u0_ & 0xffff0000u);                 \
    float d2_  = __builtin_bit_cast(float, u1_ << 16);                         \
    float d3_  = __builtin_bit_cast(float, u1_ & 0xffff0000u);                 \
    float d4_  = __builtin_bit_cast(float, u2_ << 16);                         \
    float d5_  = __builtin_bit_cast(float, u2_ & 0xffff0000u);                 \
    float d6_  = __builtin_bit_cast(float, u3_ << 16);                         \
    float d7_  = __builtin_bit_cast(float, u3_ & 0xffff0000u);                 \
    float d8_  = __builtin_bit_cast(float, u4_ << 16);                         \
    float d9_  = __builtin_bit_cast(float, u4_ & 0xffff0000u);                 \
    float d10_ = __builtin_bit_cast(float, u5_ << 16);                         \
    float d11_ = __builtin_bit_cast(float, u5_ & 0xffff0000u);                 \
    float d12_ = __builtin_bit_cast(float, u6_ << 16);                         \
    float d13_ = __builtin_bit_cast(float, u6_ & 0xffff0000u);                 \
    float d14_ = __builtin_bit_cast(float, u7_ << 16);                         \
    float d15_ = __builtin_bit_cast(float, u7_ & 0xffff0000u);                 \
    float e0_ = (E0EXPR);                                                      \
    float c0_  = d0_  + e0_;                                                   \
    float c1_  = d1_  + fminf(fminf(p1,  p0),  c0_);                           \
    float c2_  = d2_  + fminf(fminf(p2,  p1),  c1_);                           \
    float c3_  = d3_  + fminf(fminf(p3,  p2),  c2_);                           \
    float c4_  = d4_  + fminf(fminf(p4,  p3),  c3_);                           \
    float c5_  = d5_  + fminf(fminf(p5,  p4),  c4_);                           \
    float c6_  = d6_  + fminf(fminf(p6,  p5),  c5_);                           \
    float c7_  = d7_  + fminf(fminf(p7,  p6),  c6_);                           \
    float c8_  = d8_  + fminf(fminf(p8,  p7),  c7_);                           \
    float c9_  = d9_  + fminf(fminf(p9,  p8),  c8_);                           \
    float c10_ = d10_ + fminf(fminf(p10, p9),  c9_);                           \
    float c11_ = d11_ + fminf(fminf(p11, p10), c10_);                          \
    float c12_ = d12_ + fminf(fminf(p12, p11), c11_);                          \
    float c13_ = d13_ + fminf(fminf(p13, p12), c12_);                          \
    float c14_ = d14_ + fminf(fminf(p14, p13), c13_);                          \
    float c15_ = d15_ + fminf(fminf(p15, p14), c14_);                          \
    p0=c0_; p1=c1_; p2=c2_; p3=c3_; p4=c4_; p5=c5_; p6=c6_; p7=c7_;            \
    p8=c8_; p9=c9_; p10=c10_; p11=c11_; p12=c12_; p13=c13_; p14=c14_; p15=c15_;\
    a3 = a2; a2 = a1;                                                          \
    a1 = __shfl_up(c15_, 1, 64);                                               \
    a1 = lane0 ? DINF : a1;                                                    \
} while (0)

#define STEPB(P)       STEPBODY(P, fminf(fminf(p0, a3), a2))
#define STEPB_FIRST(P) STEPBODY(P, lane0 ? 0.0f : fminf(fminf(p0, a3), a2))

__global__ __launch_bounds__(64, 1) void dtw_dp_kernel(
    const __hip_bfloat16* __restrict__ skew, float* __restrict__ out) {
    __shared__ float4 ring[8][2][64];  // 16 KiB: [slot][chunk][lane]

    const int b = blockIdx.x;
    const int t = threadIdx.x;
    const bool lane0 = (t == 0);
    const char* Sb = (const char*)(skew + (size_t)b * (1152 * 1024));

    float p0 = DINF, p1 = DINF, p2 = DINF, p3 = DINF,
          p4 = DINF, p5 = DINF, p6 = DINF, p7 = DINF,
          p8 = DINF, p9 = DINF, p10 = DINF, p11 = DINF,
          p12 = DINF, p13 = DINF, p14 = DINF, p15 = DINF;
    float a1 = DINF, a2 = DINF, a3 = DINF;

    float4 X_0, X_1;   // even steps
    float4 Y_0, Y_1;   // odd steps

    // prologue: fill all 8 slots (steps 0..7), land slot 0, read it.
    LOADB(0, 0); LOADB(1, 1); LOADB(2, 2); LOADB(3, 3);
    LOADB(4, 4); LOADB(5, 5); LOADB(6, 6); LOADB(7, 7);
    VWAIT(14);
    DSREAD(0, X);

    // bodies 0..7
    LGKM0; LOADB(8,  0); VWAIT(14); DSREAD(1, Y); STEPB_FIRST(X);
    LGKM0; LOADB(9,  1); VWAIT(14); DSREAD(2, X); STEPB(Y);
    LGKM0; LOADB(10, 2); VWAIT(14); DSREAD(3, Y); STEPB(X);
    LGKM0; LOADB(11, 3); VWAIT(14); DSREAD(4, X); STEPB(Y);
    LGKM0; LOADB(12, 4); VWAIT(14); DSREAD(5, Y); STEPB(X);
    LGKM0; LOADB(13, 5); VWAIT(14); DSREAD(6, X); STEPB(Y);
    LGKM0; LOADB(14, 6); VWAIT(14); DSREAD(7, Y); STEPB(X);
    LGKM0; LOADB(15, 7); VWAIT(14); DSREAD(0, X); STEPB(Y);

    // bodies 8..1135 (141 iterations x 8 steps)
#pragma unroll 1
    for (int k = 8; k < 1136; k += 8) {
        LGKM0; LOADB(k + 8,  0); VWAIT(14); DSREAD(1, Y); STEPB(X);
        LGKM0; LOADB(k + 9,  1); VWAIT(14); DSREAD(2, X); STEPB(Y);
        LGKM0; LOADB(k + 10, 2); VWAIT(14); DSREAD(3, Y); STEPB(X);
        LGKM0; LOADB(k + 11, 3); VWAIT(14); DSREAD(4, X); STEPB(Y);
        LGKM0; LOADB(k + 12, 4); VWAIT(14); DSREAD(5, Y); STEPB(X);
        LGKM0; LOADB(k + 13, 5); VWAIT(14); DSREAD(6, X); STEPB(Y);
        LGKM0; LOADB(k + 14, 6); VWAIT(14); DSREAD(7, Y); STEPB(X);
        LGKM0; LOADB(k + 15, 7); VWAIT(14); DSREAD(0, X); STEPB(Y);
    }

    // bodies 1136..1141 (last DMA targets step 1149)
    LGKM0; LOADB(1144, 0); VWAIT(14); DSREAD(1, Y); STEPB(X);
    LGKM0; LOADB(1145, 1); VWAIT(14); DSREAD(2, X); STEPB(Y);
    LGKM0; LOADB(1146, 2); VWAIT(14); DSREAD(3, Y); STEPB(X);
    LGKM0; LOADB(1147, 3); VWAIT(14); DSREAD(4, X); STEPB(Y);
    LGKM0; LOADB(1148, 4); VWAIT(14); DSREAD(5, Y); STEPB(X);
    LGKM0; LOADB(1149, 5); VWAIT(14); DSREAD(6, X); STEPB(Y);

    // tail 1142..1149: drain (2 loads retire per body)
    VWAIT(12); DSREAD(7, Y); STEPB(X);
    VWAIT(10); DSREAD(0, X); STEPB(Y);
    VWAIT(8);  DSREAD(1, Y); STEPB(X);
    VWAIT(6);  DSREAD(2, X); STEPB(Y);
    VWAIT(4);  DSREAD(3, Y); STEPB(X);
    VWAIT(2);  DSREAD(4, X); STEPB(Y);
    VWAIT(0);  DSREAD(5, Y); STEPB(X);
    STEPB(Y);

    // Lane 63's final step is k = 1023 + 2*63 = 1149 -> p15 = dtw[1023][1023].
    if (t == 63) out[b] = 1.0f / (1.0f + p15 * (1.0f / 2048.0f));
}

// ---------------------------------------------------------------------------
extern "C" void kernel_launch(void* const* d_in, const int* in_sizes, int n_in,
                              void* d_out, int out_size, void* d_ws, size_t ws_size,
                              hipStream_t stream) {
    const float* s1 = (const float*)d_in[0];
    const float* s2 = (const float*)d_in[1];
    float* out = (float*)d_out;

    char* ws = (char*)d_ws;
    __hip_bfloat16* Abf  = (__hip_bfloat16*)(ws);                // 25165824 B
    __hip_bfloat16* Bbf  = (__hip_bfloat16*)(ws + 25165824);     // 25165824 B
    __hip_bfloat16* skew = (__hip_bfloat16*)(ws + 50331648);     // 16*1152*1024*2 = 37748736 B

    // zero the skew buffer: parallelogram holes must be benign (0) for the
    // DINF min-plus flow; first call may see arbitrary garbage otherwise.
    hipMemsetAsync(skew, 0, (size_t)16 * 1152 * 1024 * 2, stream);

    norm_bf16_kernel<<<8192, 256, 0, stream>>>(s1, s2, Abf, Bbf);
    gemm_dist_kernel<<<16 * 64, 256, 0, stream>>>(Abf, Bbf, skew);
    dtw_dp_kernel<<<16, 64, 0, stream>>>(skew, out);
}

// Round 6
// 260.785 us; speedup vs baseline: 2.0249x; 1.7833x over previous
//
#include <hip/hip_runtime.h>
#include <hip/hip_bf16.h>

typedef __attribute__((ext_vector_type(4))) float f32x4;
typedef __attribute__((ext_vector_type(8))) short bf16x8;

#define DINF 1e30f

// ---------------------------------------------------------------------------
// round-to-nearest-even fp32 -> bf16 bits (inputs are finite gaussians)
__device__ __forceinline__ unsigned short f2bf(float f) {
    unsigned int u = __builtin_bit_cast(unsigned int, f);
    u += 0x7FFFu + ((u >> 16) & 1u);
    return (unsigned short)(u >> 16);
}

// ---------------------------------------------------------------------------
// Kernel 0: zero only the skew rows that contain parallelogram holes
// (rows 0..125 and 1024..1151; rows 126..1023 are fully GEMM-written).
// 254 rows x 2KB x 16 batches = 8.3 MB (vs 37.7 MB full memset).
__global__ __launch_bounds__(256) void zero_holes_kernel(float4* __restrict__ skew) {
    const int idx = blockIdx.x;       // 16 * 127 blocks; 2 rows per block
    const int bt  = idx / 127;
    const int pr  = idx % 127;
    const int h   = pr * 2 + (threadIdx.x >> 7);        // hole-row 0..253
    const int row = h < 126 ? h : 1024 + (h - 126);     // 0..125, 1024..1151
    const int c   = threadIdx.x & 127;                  // 128 x 16B = 2KB
    skew[((size_t)bt * 1152 + row) * 128 + c] = (float4){0.f, 0.f, 0.f, 0.f};
}

// ---------------------------------------------------------------------------
// Kernel 1: L2-normalize each 768-dim row, emit bf16.
__global__ __launch_bounds__(256) void norm_bf16_kernel(
    const float* __restrict__ s1, const float* __restrict__ s2,
    __hip_bfloat16* __restrict__ o1, __hip_bfloat16* __restrict__ o2) {
    const int gb = blockIdx.x;
    const float* in;
    __hip_bfloat16* out;
    int rowbase;
    if (gb < 4096) { in = s1; out = o1; rowbase = gb * 4; }
    else           { in = s2; out = o2; rowbase = (gb - 4096) * 4; }
    const int wv = threadIdx.x >> 6;
    const int l  = threadIdx.x & 63;
    const int row = rowbase + wv;

    const float* rp = in + (size_t)row * 768 + l * 4;
    float4 x0 = *(const float4*)(rp);
    float4 x1 = *(const float4*)(rp + 256);
    float4 x2 = *(const float4*)(rp + 512);

    float s = x0.x*x0.x + x0.y*x0.y + x0.z*x0.z + x0.w*x0.w
            + x1.x*x1.x + x1.y*x1.y + x1.z*x1.z + x1.w*x1.w
            + x2.x*x2.x + x2.y*x2.y + x2.z*x2.z + x2.w*x2.w;
#pragma unroll
    for (int off = 32; off > 0; off >>= 1) s += __shfl_xor(s, off, 64);

    const float inv = 1.0f / fmaxf(sqrtf(s), 1e-12f);

    __hip_bfloat16* op = out + (size_t)row * 768 + l * 4;
    ushort4 o;
    o.x = f2bf(x0.x*inv); o.y = f2bf(x0.y*inv); o.z = f2bf(x0.z*inv); o.w = f2bf(x0.w*inv);
    *(ushort4*)(op) = o;
    o.x = f2bf(x1.x*inv); o.y = f2bf(x1.y*inv); o.z = f2bf(x1.z*inv); o.w = f2bf(x1.w*inv);
    *(ushort4*)(op + 256) = o;
    o.x = f2bf(x2.x*inv); o.y = f2bf(x2.y*inv); o.z = f2bf(x2.z*inv); o.w = f2bf(x2.w*inv);
    *(ushort4*)(op + 512) = o;
}

// ---------------------------------------------------------------------------
// Kernel 2: GEMM -> SKEWED bf16 distance matrix.
// skew[b][row + 2*(col>>4)][col] = bf16(1 - dot(A[row], B[col])).
#define GLOAD_LDS16(g, l)                                                      \
    __builtin_amdgcn_global_load_lds(                                          \
        (const __attribute__((address_space(1))) void*)(g),                    \
        (__attribute__((address_space(3))) void*)(l), 16, 0, 0)

__global__ __launch_bounds__(256) void gemm_dist_kernel(
    const __hip_bfloat16* __restrict__ A, const __hip_bfloat16* __restrict__ B,
    __hip_bfloat16* __restrict__ skew) {
    __shared__ __hip_bfloat16 lA[128 * 64];  // [row][k], rows of 128B
    __shared__ __hip_bfloat16 lB[128 * 64];

    const int blk  = (blockIdx.x & 7) * 128 + (blockIdx.x >> 3);
    const int b    = blk >> 6;
    const int tile = blk & 63;
    const int tm = tile >> 3, tn = tile & 7;
    const int tid  = threadIdx.x;
    const int lane = tid & 63, w = tid >> 6;
    const int lr = lane & 15, lg = lane >> 4;
    const int wm = w >> 1, wn = w & 1;

    const __hip_bfloat16* Ab = A + (size_t)b * (1024 * 768) + (size_t)(tm * 128) * 768;
    const __hip_bfloat16* Bb = B + (size_t)b * (1024 * 768) + (size_t)(tn * 128) * 768;

    const int srow = tid >> 3;        // 0..31 (row within 32-row chunk)
    const int scol = (tid & 7) * 8;   // k-octet (8 bf16 = 16B per lane)

    char* lAb = (char*)lA;
    char* lBb = (char*)lB;

    f32x4 acc[4][4];
#pragma unroll
    for (int m = 0; m < 4; ++m)
#pragma unroll
        for (int n = 0; n < 4; ++n) acc[m][n] = (f32x4){0.f, 0.f, 0.f, 0.f};

    for (int k0 = 0; k0 < 768; k0 += 64) {
#pragma unroll
        for (int q = 0; q < 4; ++q) {
            GLOAD_LDS16(Ab + (size_t)(q * 32 + srow) * 768 + k0 + scol,
                        lAb + q * 4096 + w * 1024);
            GLOAD_LDS16(Bb + (size_t)(q * 32 + srow) * 768 + k0 + scol,
                        lBb + q * 4096 + w * 1024);
        }
        __syncthreads();

#pragma unroll
        for (int ks = 0; ks < 64; ks += 32) {
            bf16x8 af[4], bfr[4];
#pragma unroll
            for (int m = 0; m < 4; ++m)
                af[m] = *(const bf16x8*)&lA[(wm * 64 + m * 16 + lr) * 64 + ks + lg * 8];
#pragma unroll
            for (int n = 0; n < 4; ++n)
                bfr[n] = *(const bf16x8*)&lB[(wn * 64 + n * 16 + lr) * 64 + ks + lg * 8];
#pragma unroll
            for (int m = 0; m < 4; ++m)
#pragma unroll
                for (int n = 0; n < 4; ++n)
                    acc[m][n] = __builtin_amdgcn_mfma_f32_16x16x32_bf16(af[m], bfr[n], acc[m][n], 0, 0, 0);
        }
        __syncthreads();
    }

    unsigned short* S = (unsigned short*)skew + (size_t)b * (1152 * 1024);
#pragma unroll
    for (int m = 0; m < 4; ++m)
#pragma unroll
        for (int n = 0; n < 4; ++n) {
            const int cb = tn * 128 + wn * 64 + n * 16;       // col base (mult of 16)
            const int soff = 2 * (cb >> 4);                   // skew offset for this col block
#pragma unroll
            for (int r = 0; r < 4; ++r) {
                const int row = tm * 128 + wm * 64 + m * 16 + lg * 4 + r;
                S[(size_t)(row + soff) * 1024 + cb + lr] = f2bf(1.0f - acc[m][n][r]);
            }
        }
}

// ---------------------------------------------------------------------------
// Kernel 3: DTW DP. One wave per batch. Lane t owns cols [16t,16t+16).
// Skew 2: step k -> lane t processes row r = k - 2t.
//
// ROUND-6 RESTRUCTURE: rounds 4/5 paid ~600 cyc/step of fixed sync overhead
// (per-body lgkmcnt(0) draining the fresh ds_bpermute, per-body vmcnt with
// marginal 7-body slack, 4 serialization points per ~130 cyc of work).
// Now: 3 LDS banks x 8 rows; one superbody = 8 steps with ONE vmcnt wait:
//   ISSUE8 -> bank (j+2)%3   (8 rows x 2 DMA)
//   VWAIT(16)                (in-order retire: bank j%3 landed at j-1;
//                             prefetch slack = 2 superbodies ~2000 cyc)
//   16 ds_reads -> 8 named reg buffers (no asm inside; compiler batches
//   reads and uses counted lgkmcnt around the bpermutes)
//   8 straight-line STEPs
// Per-body lgkmcnt(0) dropped: a slot's ds_read is CONSUMED (compiler-
// enforced lgkm wait) 7+ steps before its overwriting DMA is issued.

#define VWAIT(n) asm volatile("s_waitcnt vmcnt(" #n ")" ::: "memory")

#define GLDMA16(g, l)                                                          \
    __builtin_amdgcn_global_load_lds(                                          \
        (const __attribute__((address_space(1))) void*)(g),                    \
        (__attribute__((address_space(3))) void*)(l), 16, 0, 0)

// skew row RW (2KB contiguous); lane t's 32B at +t*32 (folded into Sb).
#define LOADR(BK, SL, RW) do {                                                 \
    const char* g_ = Sb + ((size_t)(RW) << 11);                                \
    GLDMA16(g_,      &ring[BK][SL][0][0]);                                     \
    GLDMA16(g_ + 16, &ring[BK][SL][1][0]);                                     \
} while (0)

#define ISSUE8(BK, BASE) do {                                                  \
    LOADR(BK, 0, (BASE));     LOADR(BK, 1, (BASE) + 1);                        \
    LOADR(BK, 2, (BASE) + 2); LOADR(BK, 3, (BASE) + 3);                        \
    LOADR(BK, 4, (BASE) + 4); LOADR(BK, 5, (BASE) + 5);                        \
    LOADR(BK, 6, (BASE) + 6); LOADR(BK, 7, (BASE) + 7);                        \
} while (0)

#define DECLR(N) float4 N##_0, N##_1

#define DSRD(BK, SL, N) do {                                                   \
    N##_0 = ring[BK][SL][0][t]; N##_1 = ring[BK][SL][1][t];                    \
} while (0)

#define DSRD8(BK) do {                                                         \
    DSRD(BK, 0, R0); DSRD(BK, 1, R1); DSRD(BK, 2, R2); DSRD(BK, 3, R3);        \
    DSRD(BK, 4, R4); DSRD(BK, 5, R5); DSRD(BK, 6, R6); DSRD(BK, 7, R7);        \
} while (0)

// Unpack 16 bf16 cols from two float4s; min-plus chain; boundary shfl.
// lin = a2 (neighbor boundary, row r), dg = a3 (row r-1).
#define STEPBODY(P, E0EXPR) do {                                               \
    unsigned u0_ = __builtin_bit_cast(unsigned, P##_0.x);                      \
    unsigned u1_ = __builtin_bit_cast(unsigned, P##_0.y);                      \
    unsigned u2_ = __builtin_bit_cast(unsigned, P##_0.z);                      \
    unsigned u3_ = __builtin_bit_cast(unsigned, P##_0.w);                      \
    unsigned u4_ = __builtin_bit_cast(unsigned, P##_1.x);                      \
    unsigned u5_ = __builtin_bit_cast(unsigned, P##_1.y);                      \
    unsigned u6_ = __builtin_bit_cast(unsigned, P##_1.z);                      \
    unsigned u7_ = __builtin_bit_cast(unsigned, P##_1.w);                      \
    float d0_  = __builtin_bit_cast(float, u0_ << 16);                         \
    float d1_  = __builtin_bit_cast(float, u0_ & 0xffff0000u);                 \
    float d2_  = __builtin_bit_cast(float, u1_ << 16);                         \
    float d3_  = __builtin_bit_cast(float, u1_ & 0xffff0000u);                 \
    float d4_  = __builtin_bit_cast(float, u2_ << 16);                         \
    float d5_  = __builtin_bit_cast(float, u2_ & 0xffff0000u);                 \
    float d6_  = __builtin_bit_cast(float, u3_ << 16);                         \
    float d7_  = __builtin_bit_cast(float, u3_ & 0xffff0000u);                 \
    float d8_  = __builtin_bit_cast(float, u4_ << 16);                         \
    float d9_  = __builtin_bit_cast(float, u4_ & 0xffff0000u);                 \
    float d10_ = __builtin_bit_cast(float, u5_ << 16);                         \
    float d11_ = __builtin_bit_cast(float, u5_ & 0xffff0000u);                 \
    float d12_ = __builtin_bit_cast(float, u6_ << 16);                         \
    float d13_ = __builtin_bit_cast(float, u6_ & 0xffff0000u);                 \
    float d14_ = __builtin_bit_cast(float, u7_ << 16);                         \
    float d15_ = __builtin_bit_cast(float, u7_ & 0xffff0000u);                 \
    float e0_ = (E0EXPR);                                                      \
    float c0_  = d0_  + e0_;                                                   \
    float c1_  = d1_  + fminf(fminf(p1,  p0),  c0_);                           \
    float c2_  = d2_  + fminf(fminf(p2,  p1),  c1_);                           \
    float c3_  = d3_  + fminf(fminf(p3,  p2),  c2_);                           \
    float c4_  = d4_  + fminf(fminf(p4,  p3),  c3_);                           \
    float c5_  = d5_  + fminf(fminf(p5,  p4),  c4_);                           \
    float c6_  = d6_  + fminf(fminf(p6,  p5),  c5_);                           \
    float c7_  = d7_  + fminf(fminf(p7,  p6),  c6_);                           \
    float c8_  = d8_  + fminf(fminf(p8,  p7),  c7_);                           \
    float c9_  = d9_  + fminf(fminf(p9,  p8),  c8_);                           \
    float c10_ = d10_ + fminf(fminf(p10, p9),  c9_);                           \
    float c11_ = d11_ + fminf(fminf(p11, p10), c10_);                          \
    float c12_ = d12_ + fminf(fminf(p12, p11), c11_);                          \
    float c13_ = d13_ + fminf(fminf(p13, p12), c12_);                          \
    float c14_ = d14_ + fminf(fminf(p14, p13), c13_);                          \
    float c15_ = d15_ + fminf(fminf(p15, p14), c14_);                          \
    p0=c0_; p1=c1_; p2=c2_; p3=c3_; p4=c4_; p5=c5_; p6=c6_; p7=c7_;            \
    p8=c8_; p9=c9_; p10=c10_; p11=c11_; p12=c12_; p13=c13_; p14=c14_; p15=c15_;\
    a3 = a2; a2 = a1;                                                          \
    a1 = __shfl_up(c15_, 1, 64);                                               \
    a1 = lane0 ? DINF : a1;                                                    \
} while (0)

#define STEPB(P)       STEPBODY(P, fminf(fminf(p0, a3), a2))
#define STEPB_FIRST(P) STEPBODY(P, lane0 ? 0.0f : fminf(fminf(p0, a3), a2))

#define STEP8() do {                                                           \
    STEPB(R0); STEPB(R1); STEPB(R2); STEPB(R3);                                \
    STEPB(R4); STEPB(R5); STEPB(R6); STEPB(R7);                                \
} while (0)

__global__ __launch_bounds__(64, 1) void dtw_dp_kernel(
    const __hip_bfloat16* __restrict__ skew, float* __restrict__ out) {
    __shared__ float4 ring[3][8][2][64];  // 48 KiB: [bank][row][chunk][lane]

    const int b = blockIdx.x;
    const int t = threadIdx.x;
    const bool lane0 = (t == 0);
    const char* Sb = (const char*)(skew + (size_t)b * (1152 * 1024)) + (t << 5);

    float p0 = DINF, p1 = DINF, p2 = DINF, p3 = DINF,
          p4 = DINF, p5 = DINF, p6 = DINF, p7 = DINF,
          p8 = DINF, p9 = DINF, p10 = DINF, p11 = DINF,
          p12 = DINF, p13 = DINF, p14 = DINF, p15 = DINF;
    float a1 = DINF, a2 = DINF, a3 = DINF;

    DECLR(R0); DECLR(R1); DECLR(R2); DECLR(R3);
    DECLR(R4); DECLR(R5); DECLR(R6); DECLR(R7);

    // prologue: rows 0-7 -> bank 0, rows 8-15 -> bank 1 (16 DMAs in flight)
    ISSUE8(0, 0);
    ISSUE8(1, 8);

    // superbody j=0 (steps 0..7): issue bank 2 (rows 16-23); VWAIT(16)
    // retires bank 0 (oldest 8 of 24) -> read it.
    ISSUE8(2, 16);
    VWAIT(16);
    DSRD8(0);
    STEPB_FIRST(R0);
    STEPB(R1); STEPB(R2); STEPB(R3); STEPB(R4); STEPB(R5); STEPB(R6); STEPB(R7);

    // superbodies j=1..141 (steps 8..1135); issue rows 24..1151.
    int rb = 1, ib = 0, base = 24;
#pragma unroll 1
    for (int j = 1; j < 142; ++j) {
        ISSUE8(ib, base);
        VWAIT(16);
        DSRD8(rb);
        STEP8();
        rb = rb == 2 ? 0 : rb + 1;
        ib = ib == 2 ? 0 : ib + 1;
        base += 8;
    }

    // tail: bank 1 holds rows 1136-1143 (issued j=140), bank 2 rows 1144-1151
    // (issued j=141). 16 in flight; VWAIT(8) retires bank 1.
    VWAIT(8);
    DSRD8(1);
    STEP8();                              // steps 1136..1143
    VWAIT(0);
    DSRD(2, 0, R0); DSRD(2, 1, R1); DSRD(2, 2, R2);
    DSRD(2, 3, R3); DSRD(2, 4, R4); DSRD(2, 5, R5);
    STEPB(R0); STEPB(R1); STEPB(R2); STEPB(R3); STEPB(R4); STEPB(R5);  // 1144..1149

    // Lane 63's final step is k = 1023 + 2*63 = 1149 -> p15 = dtw[1023][1023].
    if (t == 63) out[b] = 1.0f / (1.0f + p15 * (1.0f / 2048.0f));
}

// ---------------------------------------------------------------------------
extern "C" void kernel_launch(void* const* d_in, const int* in_sizes, int n_in,
                              void* d_out, int out_size, void* d_ws, size_t ws_size,
                              hipStream_t stream) {
    const float* s1 = (const float*)d_in[0];
    const float* s2 = (const float*)d_in[1];
    float* out = (float*)d_out;

    char* ws = (char*)d_ws;
    __hip_bfloat16* Abf  = (__hip_bfloat16*)(ws);                // 25165824 B
    __hip_bfloat16* Bbf  = (__hip_bfloat16*)(ws + 25165824);     // 25165824 B
    __hip_bfloat16* skew = (__hip_bfloat16*)(ws + 50331648);     // 16*1152*1024*2 = 37748736 B

    zero_holes_kernel<<<16 * 127, 256, 0, stream>>>((float4*)skew);
    norm_bf16_kernel<<<8192, 256, 0, stream>>>(s1, s2, Abf, Bbf);
    gemm_dist_kernel<<<16 * 64, 256, 0, stream>>>(Abf, Bbf, skew);
    dtw_dp_kernel<<<16, 64, 0, stream>>>(skew, out);
}

// Round 7
// 248.190 us; speedup vs baseline: 2.1276x; 1.0507x over previous
//
#include <hip/hip_runtime.h>
#include <hip/hip_bf16.h>

typedef __attribute__((ext_vector_type(4))) float f32x4;
typedef __attribute__((ext_vector_type(8))) short bf16x8;

#define DINF 1e30f

// ---------------------------------------------------------------------------
// round-to-nearest-even fp32 -> bf16 bits (inputs are finite gaussians)
__device__ __forceinline__ unsigned short f2bf(float f) {
    unsigned int u = __builtin_bit_cast(unsigned int, f);
    u += 0x7FFFu + ((u >> 16) & 1u);
    return (unsigned short)(u >> 16);
}

// ---------------------------------------------------------------------------
// Kernel 0: zero only the skew rows that contain parallelogram holes
// (rows 0..125 and 1024..1151; rows 126..1023 are fully GEMM-written).
__global__ __launch_bounds__(256) void zero_holes_kernel(float4* __restrict__ skew) {
    const int idx = blockIdx.x;       // 16 * 127 blocks; 2 rows per block
    const int bt  = idx / 127;
    const int pr  = idx % 127;
    const int h   = pr * 2 + (threadIdx.x >> 7);        // hole-row 0..253
    const int row = h < 126 ? h : 1024 + (h - 126);     // 0..125, 1024..1151
    const int c   = threadIdx.x & 127;                  // 128 x 16B = 2KB
    skew[((size_t)bt * 1152 + row) * 128 + c] = (float4){0.f, 0.f, 0.f, 0.f};
}

// ---------------------------------------------------------------------------
// Kernel 1: L2-normalize each 768-dim row, emit bf16.
__global__ __launch_bounds__(256) void norm_bf16_kernel(
    const float* __restrict__ s1, const float* __restrict__ s2,
    __hip_bfloat16* __restrict__ o1, __hip_bfloat16* __restrict__ o2) {
    const int gb = blockIdx.x;
    const float* in;
    __hip_bfloat16* out;
    int rowbase;
    if (gb < 4096) { in = s1; out = o1; rowbase = gb * 4; }
    else           { in = s2; out = o2; rowbase = (gb - 4096) * 4; }
    const int wv = threadIdx.x >> 6;
    const int l  = threadIdx.x & 63;
    const int row = rowbase + wv;

    const float* rp = in + (size_t)row * 768 + l * 4;
    float4 x0 = *(const float4*)(rp);
    float4 x1 = *(const float4*)(rp + 256);
    float4 x2 = *(const float4*)(rp + 512);

    float s = x0.x*x0.x + x0.y*x0.y + x0.z*x0.z + x0.w*x0.w
            + x1.x*x1.x + x1.y*x1.y + x1.z*x1.z + x1.w*x1.w
            + x2.x*x2.x + x2.y*x2.y + x2.z*x2.z + x2.w*x2.w;
#pragma unroll
    for (int off = 32; off > 0; off >>= 1) s += __shfl_xor(s, off, 64);

    const float inv = 1.0f / fmaxf(sqrtf(s), 1e-12f);

    __hip_bfloat16* op = out + (size_t)row * 768 + l * 4;
    ushort4 o;
    o.x = f2bf(x0.x*inv); o.y = f2bf(x0.y*inv); o.z = f2bf(x0.z*inv); o.w = f2bf(x0.w*inv);
    *(ushort4*)(op) = o;
    o.x = f2bf(x1.x*inv); o.y = f2bf(x1.y*inv); o.z = f2bf(x1.z*inv); o.w = f2bf(x1.w*inv);
    *(ushort4*)(op + 256) = o;
    o.x = f2bf(x2.x*inv); o.y = f2bf(x2.y*inv); o.z = f2bf(x2.z*inv); o.w = f2bf(x2.w*inv);
    *(ushort4*)(op + 512) = o;
}

// ---------------------------------------------------------------------------
// Kernel 2: GEMM -> SKEWED bf16 distance matrix.
// skew[b][row + 2*(col>>4)][col] = bf16(1 - dot(A[row], B[col])).
#define GLOAD_LDS16(g, l)                                                      \
    __builtin_amdgcn_global_load_lds(                                          \
        (const __attribute__((address_space(1))) void*)(g),                    \
        (__attribute__((address_space(3))) void*)(l), 16, 0, 0)

__global__ __launch_bounds__(256) void gemm_dist_kernel(
    const __hip_bfloat16* __restrict__ A, const __hip_bfloat16* __restrict__ B,
    __hip_bfloat16* __restrict__ skew) {
    __shared__ __hip_bfloat16 lA[128 * 64];  // [row][k], rows of 128B
    __shared__ __hip_bfloat16 lB[128 * 64];

    const int blk  = (blockIdx.x & 7) * 128 + (blockIdx.x >> 3);
    const int b    = blk >> 6;
    const int tile = blk & 63;
    const int tm = tile >> 3, tn = tile & 7;
    const int tid  = threadIdx.x;
    const int lane = tid & 63, w = tid >> 6;
    const int lr = lane & 15, lg = lane >> 4;
    const int wm = w >> 1, wn = w & 1;

    const __hip_bfloat16* Ab = A + (size_t)b * (1024 * 768) + (size_t)(tm * 128) * 768;
    const __hip_bfloat16* Bb = B + (size_t)b * (1024 * 768) + (size_t)(tn * 128) * 768;

    const int srow = tid >> 3;        // 0..31 (row within 32-row chunk)
    const int scol = (tid & 7) * 8;   // k-octet (8 bf16 = 16B per lane)

    char* lAb = (char*)lA;
    char* lBb = (char*)lB;

    f32x4 acc[4][4];
#pragma unroll
    for (int m = 0; m < 4; ++m)
#pragma unroll
        for (int n = 0; n < 4; ++n) acc[m][n] = (f32x4){0.f, 0.f, 0.f, 0.f};

    for (int k0 = 0; k0 < 768; k0 += 64) {
#pragma unroll
        for (int q = 0; q < 4; ++q) {
            GLOAD_LDS16(Ab + (size_t)(q * 32 + srow) * 768 + k0 + scol,
                        lAb + q * 4096 + w * 1024);
            GLOAD_LDS16(Bb + (size_t)(q * 32 + srow) * 768 + k0 + scol,
                        lBb + q * 4096 + w * 1024);
        }
        __syncthreads();

#pragma unroll
        for (int ks = 0; ks < 64; ks += 32) {
            bf16x8 af[4], bfr[4];
#pragma unroll
            for (int m = 0; m < 4; ++m)
                af[m] = *(const bf16x8*)&lA[(wm * 64 + m * 16 + lr) * 64 + ks + lg * 8];
#pragma unroll
            for (int n = 0; n < 4; ++n)
                bfr[n] = *(const bf16x8*)&lB[(wn * 64 + n * 16 + lr) * 64 + ks + lg * 8];
#pragma unroll
            for (int m = 0; m < 4; ++m)
#pragma unroll
                for (int n = 0; n < 4; ++n)
                    acc[m][n] = __builtin_amdgcn_mfma_f32_16x16x32_bf16(af[m], bfr[n], acc[m][n], 0, 0, 0);
        }
        __syncthreads();
    }

    unsigned short* S = (unsigned short*)skew + (size_t)b * (1152 * 1024);
#pragma unroll
    for (int m = 0; m < 4; ++m)
#pragma unroll
        for (int n = 0; n < 4; ++n) {
            const int cb = tn * 128 + wn * 64 + n * 16;       // col base (mult of 16)
            const int soff = 2 * (cb >> 4);                   // skew offset for this col block
#pragma unroll
            for (int r = 0; r < 4; ++r) {
                const int row = tm * 128 + wm * 64 + m * 16 + lg * 4 + r;
                S[(size_t)(row + soff) * 1024 + cb + lr] = f2bf(1.0f - acc[m][n][r]);
            }
        }
}

// ---------------------------------------------------------------------------
// Kernel 3: DTW DP. One wave per batch. Lane t owns cols [16t,16t+16).
// Skew 2: step k -> lane t processes row r = k - 2t.
//
// ROUND-7 CHANGE: round 6 read all 8 rows of a bank into 64 live VGPRs at
// superbody start (VGPR_Count 132) -- the pressure-aware scheduler then
// refused to overlap steps, leaving the 120-cyc in-step min-chain serial on
// top of the ~160-cyc issue (390 cyc/step measured). Now a 2-deep rolling
// lookahead: slot j consumes buf[j&1] then ds_reads row j+2 into the same
// buffer (period 2, slack ~2 steps >> 120-cyc LDS latency). Live row-regs
// 64 -> 16 VGPR. Lookahead crosses the bank boundary at slots 6,7, guarded
// by a second free VWAIT(16) (that bank's DMA was issued a full superbody,
// ~3000 cyc, earlier). DMA ring and DP math identical to round 6.
// Invariant at superbody j entry (16 DMA per bank, vmcnt units):
//   outstanding = 16 (bank nb); bank rb fully landed; X=row 8j, Y=row 8j+1.

#define VWAIT(n) asm volatile("s_waitcnt vmcnt(" #n ")" ::: "memory")

#define GLDMA16(g, l)                                                          \
    __builtin_amdgcn_global_load_lds(                                          \
        (const __attribute__((address_space(1))) void*)(g),                    \
        (__attribute__((address_space(3))) void*)(l), 16, 0, 0)

// skew row RW (2KB contiguous); lane t's 32B at +t*32 (folded into Sb).
#define LOADR(BK, SL, RW) do {                                                 \
    const char* g_ = Sb + ((size_t)(RW) << 11);                                \
    GLDMA16(g_,      &ring[BK][SL][0][0]);                                     \
    GLDMA16(g_ + 16, &ring[BK][SL][1][0]);                                     \
} while (0)

#define ISSUE8(BK, BASE) do {                                                  \
    LOADR(BK, 0, (BASE));     LOADR(BK, 1, (BASE) + 1);                        \
    LOADR(BK, 2, (BASE) + 2); LOADR(BK, 3, (BASE) + 3);                        \
    LOADR(BK, 4, (BASE) + 4); LOADR(BK, 5, (BASE) + 5);                        \
    LOADR(BK, 6, (BASE) + 6); LOADR(BK, 7, (BASE) + 7);                        \
} while (0)

#define DSRD(BK, SL, N) do {                                                   \
    N##_0 = ring[BK][SL][0][t]; N##_1 = ring[BK][SL][1][t];                    \
} while (0)

// Unpack 16 bf16 cols from two float4s; min-plus chain; boundary shfl.
// lin = a2 (neighbor boundary, row r), dg = a3 (row r-1).
#define STEPBODY(P, E0EXPR) do {                                               \
    unsigned u0_ = __builtin_bit_cast(unsigned, P##_0.x);                      \
    unsigned u1_ = __builtin_bit_cast(unsigned, P##_0.y);                      \
    unsigned u2_ = __builtin_bit_cast(unsigned, P##_0.z);                      \
    unsigned u3_ = __builtin_bit_cast(unsigned, P##_0.w);                      \
    unsigned u4_ = __builtin_bit_cast(unsigned, P##_1.x);                      \
    unsigned u5_ = __builtin_bit_cast(unsigned, P##_1.y);                      \
    unsigned u6_ = __builtin_bit_cast(unsigned, P##_1.z);                      \
    unsigned u7_ = __builtin_bit_cast(unsigned, P##_1.w);                      \
    float d0_  = __builtin_bit_cast(float, u0_ << 16);                         \
    float d1_  = __builtin_bit_cast(float, u0_ & 0xffff0000u);                 \
    float d2_  = __builtin_bit_cast(float, u1_ << 16);                         \
    float d3_  = __builtin_bit_cast(float, u1_ & 0xffff0000u);                 \
    float d4_  = __builtin_bit_cast(float, u2_ << 16);                         \
    float d5_  = __builtin_bit_cast(float, u2_ & 0xffff0000u);                 \
    float d6_  = __builtin_bit_cast(float, u3_ << 16);                         \
    float d7_  = __builtin_bit_cast(float, u3_ & 0xffff0000u);                 \
    float d8_  = __builtin_bit_cast(float, u4_ << 16);                         \
    float d9_  = __builtin_bit_cast(float, u4_ & 0xffff0000u);                 \
    float d10_ = __builtin_bit_cast(float, u5_ << 16);                         \
    float d11_ = __builtin_bit_cast(float, u5_ & 0xffff0000u);                 \
    float d12_ = __builtin_bit_cast(float, u6_ << 16);                         \
    float d13_ = __builtin_bit_cast(float, u6_ & 0xffff0000u);                 \
    float d14_ = __builtin_bit_cast(float, u7_ << 16);                         \
    float d15_ = __builtin_bit_cast(float, u7_ & 0xffff0000u);                 \
    float e0_ = (E0EXPR);                                                      \
    float c0_  = d0_  + e0_;                                                   \
    float c1_  = d1_  + fminf(fminf(p1,  p0),  c0_);                           \
    float c2_  = d2_  + fminf(fminf(p2,  p1),  c1_);                           \
    float c3_  = d3_  + fminf(fminf(p3,  p2),  c2_);                           \
    float c4_  = d4_  + fminf(fminf(p4,  p3),  c3_);                           \
    float c5_  = d5_  + fminf(fminf(p5,  p4),  c4_);                           \
    float c6_  = d6_  + fminf(fminf(p6,  p5),  c5_);                           \
    float c7_  = d7_  + fminf(fminf(p7,  p6),  c6_);                           \
    float c8_  = d8_  + fminf(fminf(p8,  p7),  c7_);                           \
    float c9_  = d9_  + fminf(fminf(p9,  p8),  c8_);                           \
    float c10_ = d10_ + fminf(fminf(p10, p9),  c9_);                           \
    float c11_ = d11_ + fminf(fminf(p11, p10), c10_);                          \
    float c12_ = d12_ + fminf(fminf(p12, p11), c11_);                          \
    float c13_ = d13_ + fminf(fminf(p13, p12), c12_);                          \
    float c14_ = d14_ + fminf(fminf(p14, p13), c13_);                          \
    float c15_ = d15_ + fminf(fminf(p15, p14), c14_);                          \
    p0=c0_; p1=c1_; p2=c2_; p3=c3_; p4=c4_; p5=c5_; p6=c6_; p7=c7_;            \
    p8=c8_; p9=c9_; p10=c10_; p11=c11_; p12=c12_; p13=c13_; p14=c14_; p15=c15_;\
    a3 = a2; a2 = a1;                                                          \
    a1 = __shfl_up(c15_, 1, 64);                                               \
    a1 = lane0 ? DINF : a1;                                                    \
} while (0)

#define STEPB(P)       STEPBODY(P, fminf(fminf(p0, a3), a2))
#define STEPB_FIRST(P) STEPBODY(P, lane0 ? 0.0f : fminf(fminf(p0, a3), a2))

__global__ __launch_bounds__(64, 1) void dtw_dp_kernel(
    const __hip_bfloat16* __restrict__ skew, float* __restrict__ out) {
    __shared__ float4 ring[3][8][2][64];  // 48 KiB: [bank][row][chunk][lane]

    const int b = blockIdx.x;
    const int t = threadIdx.x;
    const bool lane0 = (t == 0);
    const char* Sb = (const char*)(skew + (size_t)b * (1152 * 1024)) + (t << 5);

    float p0 = DINF, p1 = DINF, p2 = DINF, p3 = DINF,
          p4 = DINF, p5 = DINF, p6 = DINF, p7 = DINF,
          p8 = DINF, p9 = DINF, p10 = DINF, p11 = DINF,
          p12 = DINF, p13 = DINF, p14 = DINF, p15 = DINF;
    float a1 = DINF, a2 = DINF, a3 = DINF;

    float4 X_0, X_1;   // even slots
    float4 Y_0, Y_1;   // odd slots

    // prologue: rows 0-7 -> bank 0, rows 8-15 -> bank 1.
    ISSUE8(0, 0);
    ISSUE8(1, 8);
    VWAIT(16);                  // bank 0 landed (bank 1 in flight)
    DSRD(0, 0, X); DSRD(0, 1, Y);

    // superbody j=0 (steps 0..7): rb=0, nb=1, ib=2.
    ISSUE8(2, 16);
    STEPB_FIRST(X); DSRD(0, 2, X);
    STEPB(Y);       DSRD(0, 3, Y);
    STEPB(X);       DSRD(0, 4, X);
    STEPB(Y);       DSRD(0, 5, Y);
    STEPB(X);       DSRD(0, 6, X);
    STEPB(Y);       DSRD(0, 7, Y);
    VWAIT(16);                  // bank 1 landed (bank 2 in flight)
    STEPB(X);       DSRD(1, 0, X);
    STEPB(Y);       DSRD(1, 1, Y);

    // superbodies j=1..141 (steps 8..1135; last issues rows 1144..1151)
    int rb = 1, nb = 2, ib = 0, base = 24;
#pragma unroll 1
    for (int j = 1; j < 142; ++j) {
        ISSUE8(ib, base);
        STEPB(X); DSRD(rb, 2, X);
        STEPB(Y); DSRD(rb, 3, Y);
        STEPB(X); DSRD(rb, 4, X);
        STEPB(Y); DSRD(rb, 5, Y);
        STEPB(X); DSRD(rb, 6, X);
        STEPB(Y); DSRD(rb, 7, Y);
        VWAIT(16);              // bank nb landed (bank ib in flight)
        STEPB(X); DSRD(nb, 0, X);
        STEPB(Y); DSRD(nb, 1, Y);
        const int orb = rb;
        rb = nb; nb = ib; ib = orb;
        base += 8;
    }

    // superbody j=142 (steps 1136..1143): rb=1, nb=2; nothing left to issue.
    STEPB(X); DSRD(1, 2, X);
    STEPB(Y); DSRD(1, 3, Y);
    STEPB(X); DSRD(1, 4, X);
    STEPB(Y); DSRD(1, 5, Y);
    STEPB(X); DSRD(1, 6, X);
    STEPB(Y); DSRD(1, 7, Y);
    VWAIT(0);                   // bank 2 (rows 1144..1151) landed
    STEPB(X); DSRD(2, 0, X);
    STEPB(Y); DSRD(2, 1, Y);

    // tail: steps 1144..1149 from bank 2 (all landed)
    STEPB(X); DSRD(2, 2, X);
    STEPB(Y); DSRD(2, 3, Y);
    STEPB(X); DSRD(2, 4, X);
    STEPB(Y); DSRD(2, 5, Y);
    STEPB(X);
    STEPB(Y);

    // Lane 63's final step is k = 1023 + 2*63 = 1149 -> p15 = dtw[1023][1023].
    if (t == 63) out[b] = 1.0f / (1.0f + p15 * (1.0f / 2048.0f));
}

// ---------------------------------------------------------------------------
extern "C" void kernel_launch(void* const* d_in, const int* in_sizes, int n_in,
                              void* d_out, int out_size, void* d_ws, size_t ws_size,
                              hipStream_t stream) {
    const float* s1 = (const float*)d_in[0];
    const float* s2 = (const float*)d_in[1];
    float* out = (float*)d_out;

    char* ws = (char*)d_ws;
    __hip_bfloat16* Abf  = (__hip_bfloat16*)(ws);                // 25165824 B
    __hip_bfloat16* Bbf  = (__hip_bfloat16*)(ws + 25165824);     // 25165824 B
    __hip_bfloat16* skew = (__hip_bfloat16*)(ws + 50331648);     // 16*1152*1024*2 = 37748736 B

    zero_holes_kernel<<<16 * 127, 256, 0, stream>>>((float4*)skew);
    norm_bf16_kernel<<<8192, 256, 0, stream>>>(s1, s2, Abf, Bbf);
    gemm_dist_kernel<<<16 * 64, 256, 0, stream>>>(Abf, Bbf, skew);
    dtw_dp_kernel<<<16, 64, 0, stream>>>(skew, out);
}